// Round 6
// baseline (332.008 us; speedup 1.0000x reference)
//
#include <hip/hip_runtime.h>
#include <cstdint>
#include <cstddef>

#define T_LEN 8192
#define BATCH 64
#define HID   10
#define CH    66
#define EEG   64
#define SM_STRIDE 8384   // 192-entry zero pad + 8192 live, per batch (16B-aligned stride)

// ---------------------------------------------------------------------------
// K1: front projection  y[b][h][t] = b_front[h] + sum_c x[b,0,c+1,t]*w_front[h,c]
// grid (8, 64), block 256, 4 t per thread (float4 loads, float4 coalesced stores).
// ---------------------------------------------------------------------------
__global__ void k_front(const float* __restrict__ x, const float* __restrict__ wf_g,
                        const float* __restrict__ bf_g, float* __restrict__ y) {
    __shared__ float wf[EEG][HID];   // wf[c][h]
    __shared__ float bf[HID];
    int tid = threadIdx.x;
    for (int i = tid; i < EEG * HID; i += 256) {
        int h = i / EEG, c = i % EEG;      // w_front layout (H, C)
        wf[c][h] = wf_g[i];
    }
    if (tid < HID) bf[tid] = bf_g[tid];
    __syncthreads();

    int b = blockIdx.y;
    int t4 = (blockIdx.x * 256 + tid) * 4;
    const float* xb = x + ((size_t)b * CH + 1) * T_LEN + t4;   // skip aud channel 0
    float acc[4][HID];
#pragma unroll
    for (int j = 0; j < 4; ++j)
#pragma unroll
        for (int h = 0; h < HID; ++h) acc[j][h] = bf[h];
#pragma unroll 4
    for (int c = 0; c < EEG; ++c) {
        float4 xv = *(const float4*)(xb + (size_t)c * T_LEN);
#pragma unroll
        for (int h = 0; h < HID; ++h) {
            float w = wf[c][h];
            acc[0][h] = fmaf(xv.x, w, acc[0][h]);
            acc[1][h] = fmaf(xv.y, w, acc[1][h]);
            acc[2][h] = fmaf(xv.z, w, acc[2][h]);
            acc[3][h] = fmaf(xv.w, w, acc[3][h]);
        }
    }
    float* yo = y + (size_t)b * HID * T_LEN + t4;   // [b][h][t]: lane-consecutive t4
#pragma unroll
    for (int h = 0; h < HID; ++h)
        *(float4*)(yo + (size_t)h * T_LEN) =
            make_float4(acc[0][h], acc[1][h], acc[2][h], acc[3][h]);
}

// ---------------------------------------------------------------------------
// K2: front LIF, 32 chunks of 256 steps, warm 32 (exact to 0.25^32 ~ 5e-20).
// grid 512 (= 32 chunks x 16 batch-quads), block 64 (4 groups of 16 lanes).
// y is [b][h][t]: each lane streams its own contiguous row via float4 with
// 2-deep prefetch. Chunk-0 blocks also zero the 192-entry smask pad.
// ---------------------------------------------------------------------------
__global__ __launch_bounds__(64) void k_flif(const float* __restrict__ y,
                                             unsigned short* __restrict__ smask) {
    int c    = blockIdx.x >> 4;      // chunk 0..31
    int bq   = blockIdx.x & 15;      // batch quad
    int lane = threadIdx.x;
    int g = lane >> 4, h = lane & 15;
    int b = bq * 4 + g;
    int hh = h < HID ? h : HID - 1;  // inactive lanes duplicate h=9 (bits masked later)

    if (c == 0) {                    // zero the pad region for this block's 4 batches
        for (int i = lane; i < 4 * 96; i += 64) {
            int j = i / 96, w = i % 96;
            ((unsigned*)(smask + (size_t)(bq * 4 + j) * SM_STRIDE))[w] = 0u;
        }
    }

    int t0 = c * 256;
    int ts = t0 - 32; if (ts < 0) ts = 0;
    int nf = (t0 + 256 - ts) >> 2;   // # float4 steps (64 for c=0, else 72)
    const float4* yb = (const float4*)(y + ((size_t)b * HID + hh) * T_LEN + ts);

    float4 A = yb[0], B = yb[1];
    float u = 0.f, o = 0.f;
    unsigned short* smb = smask + (size_t)b * SM_STRIDE + 192;
    for (int f = 0; f < nf; ++f) {
        int nx = f + 2; if (nx > nf - 1) nx = nf - 1;
        float4 C = yb[nx];
        float vv[4] = {A.x, A.y, A.z, A.w};
        int tb = ts + f * 4;
#pragma unroll
        for (int k = 0; k < 4; ++k) {
            u = (o > 0.5f) ? vv[k] : fmaf(0.25f, u, vv[k]);   // 0.25*u exact
            bool sp = (u > 0.2f);
            o = sp ? 1.0f : 0.0f;
            unsigned long long bal = __ballot(sp);
            int t = tb + k;
            if (t >= t0 && h == 0)
                smb[t] = (unsigned short)((bal >> (g * 16)) & 0x3FFull);
        }
        A = B; B = C;
    }
}

// ---------------------------------------------------------------------------
// K3: LSNN scan + classifier. 128 chunks x 64 live steps, warm 192 (zero pad
// for early chunks -> uniform 256-step loop). Numerics identical to round 5.
// FOUR (b,chunk) units per wave, 16 lanes each (r<10 hidden, r=10,11
// classifier, r=12..15 shadow). Spike-mask collection via DPP row_ror
// OR-butterfly (pure VALU, no ballot/SGPR round-trip on the chain).
// smask prefetched 4 groups deep. T table stride 13 (bank-conflict pad).
// ---------------------------------------------------------------------------
__device__ __forceinline__ unsigned row_or16(unsigned x) {
    x |= (unsigned)__builtin_amdgcn_update_dpp(0, (int)x, 0x128, 0xF, 0xF, true); // row_ror:8
    x |= (unsigned)__builtin_amdgcn_update_dpp(0, (int)x, 0x124, 0xF, 0xF, true); // row_ror:4
    x |= (unsigned)__builtin_amdgcn_update_dpp(0, (int)x, 0x122, 0xF, 0xF, true); // row_ror:2
    x |= (unsigned)__builtin_amdgcn_update_dpp(0, (int)x, 0x121, 0xF, 0xF, true); // row_ror:1
    return x;
}

__global__ __launch_bounds__(64) void k_lsnn(
    const unsigned short* __restrict__ smask,
    const float* __restrict__ w_in, const float* __restrict__ w_rec,
    const float* __restrict__ w_cls, const float* __restrict__ b_cls,
    float* __restrict__ out) {
    __shared__ float T[832];    // [hi?416:0 + m5*13 + r], stride 13 = bank pad
    int lane = threadIdx.x;
    for (int i = lane; i < 832; i += 64) {
        int hi = i / 416;
        int rem = i - hi * 416;
        int m = rem / 13, r2 = rem - m * 13;
        float s = 0.f;
        if (r2 < 12) {
            const float* wrow = (r2 < HID) ? (w_in + r2 * HID) : (w_cls + (r2 - HID) * HID);
#pragma unroll
            for (int j = 0; j < 5; ++j)
                if (m & (1u << j)) s += wrow[hi * 5 + j];
        }
        T[i] = s;
    }
    __syncthreads();

    int q = lane >> 4;                 // unit 0..3
    int r = lane & 15;                 // role: 0..9 hidden, 10..11 cls, 12..15 shadow
    int rr = r < 12 ? r : 11;          // table-read role (shadows duplicate lane 11)
    unsigned lanebit = (r < HID) ? (1u << r) : 0u;
    int id = blockIdx.x * 4 + q;       // 2048*4 = 8192 exactly, no tail
    int b = id >> 7, chunk = id & 127;

    float wb[HID];
#pragma unroll
    for (int j = 0; j < HID; ++j)
        wb[j] = (r < HID) ? w_rec[r * HID + j] : 0.f;
    float bcl = (r == 10 || r == 11) ? b_cls[r - HID] : 0.f;

    const unsigned short* sm = smask + (size_t)b * SM_STRIDE + (size_t)chunk * 64;

    auto xlook = [&](const uint4& mv, float* X) {
        unsigned hw[8] = { mv.x & 0x3FFu, (mv.x >> 16) & 0x3FFu,
                           mv.y & 0x3FFu, (mv.y >> 16) & 0x3FFu,
                           mv.z & 0x3FFu, (mv.z >> 16) & 0x3FFu,
                           mv.w & 0x3FFu, (mv.w >> 16) & 0x3FFu };
#pragma unroll
        for (int u = 0; u < 8; ++u)
            X[u] = T[(hw[u] & 31u) * 13 + rr] + T[416 + (hw[u] >> 5) * 13 + rr];
    };

    // 4-deep mask prefetch ring
    uint4 mB = *(const uint4*)(sm + 8);
    uint4 mC = *(const uint4*)(sm + 16);
    uint4 mD = *(const uint4*)(sm + 24);
    float Xc[8], Xn[8], Pc[8], Pn[8];
    { uint4 m0 = *(const uint4*)(sm); xlook(m0, Xc); }
#pragma unroll
    for (int u = 0; u < 8; ++u) { Pc[u] = 0.f; Pn[u] = 0.f; }

    float v = 0.f, cur = 0.f;
    unsigned zmask = 0;
    float uc = 0.f, oc = 0.f, accs = 0.f;

    for (int gr = 0; gr < 32; ++gr) {
        int nb = gr + 4; if (nb > 31) nb = 31;
        uint4 mE = *(const uint4*)(sm + (size_t)nb * 8);
        xlook(mB, Xn);                  // x_in for next group (off-chain, 3 groups of slack)
        unsigned zs[8];
#pragma unroll
        for (int u = 0; u < 8; ++u) {
            int zm = (int)zmask;
            float a0 = __int_as_float(__builtin_amdgcn_sbfe(zm, 0, 1) & __float_as_int(wb[0]));
            float a1 = __int_as_float(__builtin_amdgcn_sbfe(zm, 1, 1) & __float_as_int(wb[1]));
            float a2 = __int_as_float(__builtin_amdgcn_sbfe(zm, 2, 1) & __float_as_int(wb[2]));
            float a3 = __int_as_float(__builtin_amdgcn_sbfe(zm, 3, 1) & __float_as_int(wb[3]));
            float a4 = __int_as_float(__builtin_amdgcn_sbfe(zm, 4, 1) & __float_as_int(wb[4]));
            float a5 = __int_as_float(__builtin_amdgcn_sbfe(zm, 5, 1) & __float_as_int(wb[5]));
            float a6 = __int_as_float(__builtin_amdgcn_sbfe(zm, 6, 1) & __float_as_int(wb[6]));
            float a7 = __int_as_float(__builtin_amdgcn_sbfe(zm, 7, 1) & __float_as_int(wb[7]));
            float a8 = __int_as_float(__builtin_amdgcn_sbfe(zm, 8, 1) & __float_as_int(wb[8]));
            float a9 = __int_as_float(__builtin_amdgcn_sbfe(zm, 9, 1) & __float_as_int(wb[9]));
            float s0 = a0 + a1, s1 = a2 + a3, s2 = a4 + a5, s3 = a6 + a7, s4 = a8 + a9;
            float rec = ((s0 + s1) + (s2 + s3)) + s4;

            float ij = (cur + Xc[u]) + rec;
            float vd = v + 0.1f * (ij - v);     // bit-exact form (matches reference)
            cur = ij - 0.2f * ij;               // bit-exact form
            bool zb = vd > 0.2f;                // b_dec == VTH exactly
            unsigned bit = zb ? lanebit : 0u;
            v = zb ? 0.f : vd;
            zmask = row_or16(bit);              // DPP OR-butterfly, no SGPR round-trip
            zs[u] = zmask;
        }
        if (gr >= 21) {                        // classifier-input lookups (batched)
#pragma unroll
            for (int u = 0; u < 8; ++u)
                Pn[u] = T[(zs[u] & 31u) * 13 + rr] + T[416 + (zs[u] >> 5) * 13 + rr];
        }
        if (gr >= 22) {                        // classifier LIF for group gr-1
            bool in = (gr >= 25);              // live groups are 24..31
#pragma unroll
            for (int u = 0; u < 8; ++u) {
                float ci = Pc[u] + bcl;
                uc = (oc > 0.5f) ? ci : fmaf(0.25f, uc, ci);
                oc = (uc > 0.2f) ? 1.f : 0.f;
                if (in) accs += oc;
            }
        }
#pragma unroll
        for (int u = 0; u < 8; ++u) { Xc[u] = Xn[u]; Pc[u] = Pn[u]; }
        mB = mC; mC = mD; mD = mE;
    }
    // epilogue: classifier for group 31 (live)
#pragma unroll
    for (int u = 0; u < 8; ++u) {
        float ci = Pc[u] + bcl;
        uc = (oc > 0.5f) ? ci : fmaf(0.25f, uc, ci);
        oc = (uc > 0.2f) ? 1.f : 0.f;
        accs += oc;
    }
    if (r == 10 || r == 11)
        atomicAdd(&out[b * 2 + (r - 10)], accs * (1.0f / 8192.0f));
}

// ---------------------------------------------------------------------------
extern "C" void kernel_launch(void* const* d_in, const int* in_sizes, int n_in,
                              void* d_out, int out_size, void* d_ws, size_t ws_size,
                              hipStream_t stream) {
    const float* x       = (const float*)d_in[0];
    const float* w_front = (const float*)d_in[1];
    const float* b_front = (const float*)d_in[2];
    const float* w_in    = (const float*)d_in[3];
    const float* w_rec   = (const float*)d_in[4];
    const float* w_cls   = (const float*)d_in[5];
    const float* b_cls   = (const float*)d_in[6];
    float* out = (float*)d_out;

    float* y = (float*)d_ws;                                   // 64*10*8192*4 = 20 MB, [b][h][t]
    unsigned short* smask =
        (unsigned short*)((char*)d_ws + (size_t)BATCH * HID * T_LEN * sizeof(float));

    hipMemsetAsync(out, 0, (size_t)out_size * sizeof(float), stream);
    k_front<<<dim3(T_LEN / 1024, BATCH), 256, 0, stream>>>(x, w_front, b_front, y);
    k_flif<<<dim3(512), 64, 0, stream>>>(y, smask);
    k_lsnn<<<dim3(2048), 64, 0, stream>>>(smask, w_in, w_rec, w_cls, b_cls, out);
}

// Round 7
// 314.110 us; speedup vs baseline: 1.0570x; 1.0570x over previous
//
#include <hip/hip_runtime.h>
#include <cstdint>
#include <cstddef>

#define T_LEN 8192
#define BATCH 64
#define HID   10
#define CH    66
#define EEG   64
#define SM_STRIDE 8384   // 192-entry zero pad + 8192 live, per batch (16B-aligned stride)

// ---------------------------------------------------------------------------
// K1: front projection  y[b][h][t] = b_front[h] + sum_c x[b,0,c+1,t]*w_front[h,c]
// grid (8, 64), block 256, 4 t per thread (float4 loads, float4 coalesced stores).
// ---------------------------------------------------------------------------
__global__ void k_front(const float* __restrict__ x, const float* __restrict__ wf_g,
                        const float* __restrict__ bf_g, float* __restrict__ y) {
    __shared__ float wf[EEG][HID];   // wf[c][h]
    __shared__ float bf[HID];
    int tid = threadIdx.x;
    for (int i = tid; i < EEG * HID; i += 256) {
        int h = i / EEG, c = i % EEG;      // w_front layout (H, C)
        wf[c][h] = wf_g[i];
    }
    if (tid < HID) bf[tid] = bf_g[tid];
    __syncthreads();

    int b = blockIdx.y;
    int t4 = (blockIdx.x * 256 + tid) * 4;
    const float* xb = x + ((size_t)b * CH + 1) * T_LEN + t4;   // skip aud channel 0
    float acc[4][HID];
#pragma unroll
    for (int j = 0; j < 4; ++j)
#pragma unroll
        for (int h = 0; h < HID; ++h) acc[j][h] = bf[h];
#pragma unroll 4
    for (int c = 0; c < EEG; ++c) {
        float4 xv = *(const float4*)(xb + (size_t)c * T_LEN);
#pragma unroll
        for (int h = 0; h < HID; ++h) {
            float w = wf[c][h];
            acc[0][h] = fmaf(xv.x, w, acc[0][h]);
            acc[1][h] = fmaf(xv.y, w, acc[1][h]);
            acc[2][h] = fmaf(xv.z, w, acc[2][h]);
            acc[3][h] = fmaf(xv.w, w, acc[3][h]);
        }
    }
    float* yo = y + (size_t)b * HID * T_LEN + t4;   // [b][h][t]: lane-consecutive t4
#pragma unroll
    for (int h = 0; h < HID; ++h)
        *(float4*)(yo + (size_t)h * T_LEN) =
            make_float4(acc[0][h], acc[1][h], acc[2][h], acc[3][h]);
}

// ---------------------------------------------------------------------------
// K2: front LIF, 32 chunks of 256 steps, warm 32 (exact to 0.25^32 ~ 5e-20).
// grid 512 (= 32 chunks x 16 batch-quads), block 64 (4 groups of 16 lanes).
// y is [b][h][t]: each lane streams its own contiguous row via float4 with
// 2-deep prefetch. Chunk-0 blocks also zero the 192-entry smask pad.
// ---------------------------------------------------------------------------
__global__ __launch_bounds__(64) void k_flif(const float* __restrict__ y,
                                             unsigned short* __restrict__ smask) {
    int c    = blockIdx.x >> 4;      // chunk 0..31
    int bq   = blockIdx.x & 15;      // batch quad
    int lane = threadIdx.x;
    int g = lane >> 4, h = lane & 15;
    int b = bq * 4 + g;
    int hh = h < HID ? h : HID - 1;  // inactive lanes duplicate h=9 (bits masked later)

    if (c == 0) {                    // zero the pad region for this block's 4 batches
        for (int i = lane; i < 4 * 96; i += 64) {
            int j = i / 96, w = i % 96;
            ((unsigned*)(smask + (size_t)(bq * 4 + j) * SM_STRIDE))[w] = 0u;
        }
    }

    int t0 = c * 256;
    int ts = t0 - 32; if (ts < 0) ts = 0;
    int nf = (t0 + 256 - ts) >> 2;   // # float4 steps (64 for c=0, else 72)
    const float4* yb = (const float4*)(y + ((size_t)b * HID + hh) * T_LEN + ts);

    float4 A = yb[0], B = yb[1];
    float u = 0.f, o = 0.f;
    unsigned short* smb = smask + (size_t)b * SM_STRIDE + 192;
    for (int f = 0; f < nf; ++f) {
        int nx = f + 2; if (nx > nf - 1) nx = nf - 1;
        float4 C = yb[nx];
        float vv[4] = {A.x, A.y, A.z, A.w};
        int tb = ts + f * 4;
#pragma unroll
        for (int k = 0; k < 4; ++k) {
            u = (o > 0.5f) ? vv[k] : fmaf(0.25f, u, vv[k]);   // 0.25*u exact
            bool sp = (u > 0.2f);
            o = sp ? 1.0f : 0.0f;
            unsigned long long bal = __ballot(sp);
            int t = tb + k;
            if (t >= t0 && h == 0)
                smb[t] = (unsigned short)((bal >> (g * 16)) & 0x3FFull);
        }
        A = B; B = C;
    }
}

// ---------------------------------------------------------------------------
// K3: LSNN scan + classifier. 128 chunks x 64 live steps, warm 192 (zero pad
// for early chunks -> uniform 256-step loop). Chunking/prefetch as round 5/6.
// FOUR (b,chunk) units per wave, 16 lanes each (r<10 hidden, r=10,11 cls,
// r=12..15 shadow). Ballot for spike mask (SALU extract, off the VALU).
// REC DOT IS NOW 2 LDS LOOKUPS + 1 ADD (table roles 12..21 = w_rec rows),
// cutting ~30 VALU/step from round 6's select-tree. Table: [hi][m5][role24],
// 6 KB. Per-step VALU ~20 (was ~50-56 in R5/R6).
// ---------------------------------------------------------------------------
__global__ __launch_bounds__(64) void k_lsnn(
    const unsigned short* __restrict__ smask,
    const float* __restrict__ w_in, const float* __restrict__ w_rec,
    const float* __restrict__ w_cls, const float* __restrict__ b_cls,
    float* __restrict__ out) {
    __shared__ float T[1536];   // [hi*768 + m*24 + role]; roles: 0-9 w_in, 10-11 w_cls,
                                // 12-21 w_rec, 22-23 zero
    int lane = threadIdx.x;
    for (int i = lane; i < 1536; i += 64) {
        int hi = i / 768;
        int rem = i - hi * 768;
        int m = rem / 24, role = rem - m * 24;
        float s = 0.f;
        if (role < 22) {
            const float* wrow = (role < 10) ? (w_in + role * HID)
                              : (role < 12) ? (w_cls + (role - 10) * HID)
                                            : (w_rec + (role - 12) * HID);
#pragma unroll
            for (int j = 0; j < 5; ++j)
                if (m & (1u << j)) s += wrow[hi * 5 + j];
        }
        T[i] = s;
    }
    __syncthreads();

    int q = lane >> 4;                 // unit 0..3
    int r = lane & 15;                 // role: 0..9 hidden, 10..11 cls, 12..15 shadow
    int rr = r < 12 ? r : 11;          // X/P table role (shadows duplicate 11)
    int rrec = 12 + (r < HID ? r : 9); // rec table role (cls/shadows dup row 9, unused)
    int shq = q * 16;
    int id = blockIdx.x * 4 + q;       // 2048*4 = 8192 exactly, no tail
    int b = id >> 7, chunk = id & 127;

    float bcl = (r == 10 || r == 11) ? b_cls[r - HID] : 0.f;

    const unsigned short* sm = smask + (size_t)b * SM_STRIDE + (size_t)chunk * 64;

    auto xlook = [&](const uint4& mv, float* X) {
        unsigned hw[8] = { mv.x & 0x3FFu, (mv.x >> 16) & 0x3FFu,
                           mv.y & 0x3FFu, (mv.y >> 16) & 0x3FFu,
                           mv.z & 0x3FFu, (mv.z >> 16) & 0x3FFu,
                           mv.w & 0x3FFu, (mv.w >> 16) & 0x3FFu };
#pragma unroll
        for (int u = 0; u < 8; ++u)
            X[u] = T[(hw[u] & 31u) * 24 + rr] + T[768 + (hw[u] >> 5) * 24 + rr];
    };

    // 4-deep mask prefetch ring
    uint4 mB = *(const uint4*)(sm + 8);
    uint4 mC = *(const uint4*)(sm + 16);
    uint4 mD = *(const uint4*)(sm + 24);
    float Xc[8], Xn[8], Pc[8], Pn[8];
    { uint4 m0 = *(const uint4*)(sm); xlook(m0, Xc); }
#pragma unroll
    for (int u = 0; u < 8; ++u) { Pc[u] = 0.f; Pn[u] = 0.f; }

    float v = 0.f, cur = 0.f;
    unsigned zmask = 0;
    float uc = 0.f, oc = 0.f, accs = 0.f;

    for (int gr = 0; gr < 32; ++gr) {
        int nb = gr + 4; if (nb > 31) nb = 31;
        uint4 mE = *(const uint4*)(sm + (size_t)nb * 8);
        xlook(mB, Xn);                  // x_in for next group (off-chain, 3 groups slack)
        unsigned zs[8];
#pragma unroll
        for (int u = 0; u < 8; ++u) {
            // rec dot via split subset-sum table: 2 ds_read + 1 add
            float rec = T[(zmask & 31u) * 24 + rrec] + T[768 + (zmask >> 5) * 24 + rrec];
            float ij = (cur + Xc[u]) + rec;
            float vd = v + 0.1f * (ij - v);     // bit-exact form (matches reference)
            cur = ij - 0.2f * ij;               // bit-exact form
            bool zb = vd > 0.2f;                // b_dec == VTH exactly
            unsigned long long bal = __ballot(zb);
            v = zb ? 0.f : vd;
            zmask = (unsigned)(bal >> shq) & 0x3FFu;
            zs[u] = zmask;
        }
        if (gr >= 21) {                        // classifier-input lookups (batched)
#pragma unroll
            for (int u = 0; u < 8; ++u)
                Pn[u] = T[(zs[u] & 31u) * 24 + rr] + T[768 + (zs[u] >> 5) * 24 + rr];
        }
        if (gr >= 22) {                        // classifier LIF for group gr-1
            bool in = (gr >= 25);              // live groups are 24..31
#pragma unroll
            for (int u = 0; u < 8; ++u) {
                float ci = Pc[u] + bcl;
                uc = (oc > 0.5f) ? ci : fmaf(0.25f, uc, ci);
                oc = (uc > 0.2f) ? 1.f : 0.f;
                if (in) accs += oc;
            }
        }
#pragma unroll
        for (int u = 0; u < 8; ++u) { Xc[u] = Xn[u]; Pc[u] = Pn[u]; }
        mB = mC; mC = mD; mD = mE;
    }
    // epilogue: classifier for group 31 (live)
#pragma unroll
    for (int u = 0; u < 8; ++u) {
        float ci = Pc[u] + bcl;
        uc = (oc > 0.5f) ? ci : fmaf(0.25f, uc, ci);
        oc = (uc > 0.2f) ? 1.f : 0.f;
        accs += oc;
    }
    if (r == 10 || r == 11)
        atomicAdd(&out[b * 2 + (r - 10)], accs * (1.0f / 8192.0f));
}

// ---------------------------------------------------------------------------
extern "C" void kernel_launch(void* const* d_in, const int* in_sizes, int n_in,
                              void* d_out, int out_size, void* d_ws, size_t ws_size,
                              hipStream_t stream) {
    const float* x       = (const float*)d_in[0];
    const float* w_front = (const float*)d_in[1];
    const float* b_front = (const float*)d_in[2];
    const float* w_in    = (const float*)d_in[3];
    const float* w_rec   = (const float*)d_in[4];
    const float* w_cls   = (const float*)d_in[5];
    const float* b_cls   = (const float*)d_in[6];
    float* out = (float*)d_out;

    float* y = (float*)d_ws;                                   // 64*10*8192*4 = 20 MB, [b][h][t]
    unsigned short* smask =
        (unsigned short*)((char*)d_ws + (size_t)BATCH * HID * T_LEN * sizeof(float));

    hipMemsetAsync(out, 0, (size_t)out_size * sizeof(float), stream);
    k_front<<<dim3(T_LEN / 1024, BATCH), 256, 0, stream>>>(x, w_front, b_front, y);
    k_flif<<<dim3(512), 64, 0, stream>>>(y, smask);
    k_lsnn<<<dim3(2048), 64, 0, stream>>>(smask, w_in, w_rec, w_cls, b_cls, out);
}